// Round 1
// baseline (575.596 us; speedup 1.0000x reference)
//
#include <hip/hip_runtime.h>

#define BATCH 16384
#define KDIM  8192
#define ODIM  32
#define NW    8            // waves per block in main kernel
#define KC    (KDIM / NW)  // 1024 k per wave

// ---------------------------------------------------------------------------
// Prep 1: build sign-transpose table bwT[k][o] = sign(w[o][k]) (as +-1.0f / 0)
// and per-block partial sums of |w|.  grid 1024 x 256 covers 32*8192 elems.
// ---------------------------------------------------------------------------
__global__ void prep_kernel(const float* __restrict__ w,
                            float* __restrict__ bwT,
                            float* __restrict__ partial) {
    int idx = blockIdx.x * 256 + threadIdx.x;   // 0 .. 262143, coalesced read
    int o = idx >> 13;                          // / KDIM
    int k = idx & (KDIM - 1);
    float v = w[idx];
    float s = (v > 0.f) ? 1.f : ((v < 0.f) ? -1.f : 0.f);
    bwT[(size_t)k * ODIM + o] = s;

    float a = fabsf(v);
    #pragma unroll
    for (int off = 32; off; off >>= 1) a += __shfl_down(a, off, 64);
    __shared__ float red[4];
    int lane = threadIdx.x & 63, wv = threadIdx.x >> 6;
    if (lane == 0) red[wv] = a;
    __syncthreads();
    if (threadIdx.x == 0)
        partial[blockIdx.x] = (red[0] + red[1]) + (red[2] + red[3]);
}

// ---------------------------------------------------------------------------
// Prep 2: deterministic reduce of 1024 partials -> scale = mean(|w|)
// ---------------------------------------------------------------------------
__global__ void scale_kernel(const float* __restrict__ partial,
                             float* __restrict__ scale) {
    int t = threadIdx.x;  // 256 threads
    float a = (partial[t] + partial[t + 256]) + (partial[t + 512] + partial[t + 768]);
    #pragma unroll
    for (int off = 32; off; off >>= 1) a += __shfl_down(a, off, 64);
    __shared__ float red[4];
    if ((t & 63) == 0) red[t >> 6] = a;
    __syncthreads();
    if (t == 0)
        scale[0] = ((red[0] + red[1]) + (red[2] + red[3])) / (float)(ODIM * KDIM);
}

// ---------------------------------------------------------------------------
// Main: lane = batch row (weights wave-uniform -> SGPR), waves split K 8-ways,
// LDS cross-wave reduce, plain stores (deterministic, no atomics).
// grid = BATCH/64 = 256 blocks x 512 threads.
// ---------------------------------------------------------------------------
__global__ __launch_bounds__(NW * 64, 1)
void main_kernel(const float* __restrict__ x,
                 const float* __restrict__ bwT,
                 const float* __restrict__ scale_p,
                 float* __restrict__ out) {
    __shared__ float part[NW][ODIM][64];   // 64 KiB

    const int tid  = threadIdx.x;
    const int wv   = tid >> 6;
    const int lane = tid & 63;
    const int row  = blockIdx.x * 64 + lane;
    const int kbase = wv * KC;

    const float* __restrict__ xr  = x + (size_t)row * KDIM + kbase;
    const float* __restrict__ wp0 = bwT + (size_t)kbase * ODIM;

    float acc[ODIM];
    #pragma unroll
    for (int o = 0; o < ODIM; ++o) acc[o] = 0.f;

    // software-pipelined: keep next iteration's x loads in flight over the FMAs
    float4 xa = *(const float4*)(xr);
    float4 xb = *(const float4*)(xr + 4);

    for (int kk = 0; kk < KC; kk += 8) {
        int nk = (kk + 8 < KC) ? (kk + 8) : kk;          // last iter: harmless reload
        float4 na = *(const float4*)(xr + nk);
        float4 nb = *(const float4*)(xr + nk + 4);

        const float* __restrict__ wp = wp0 + (size_t)kk * ODIM;
        float xs[8] = {xa.x, xa.y, xa.z, xa.w, xb.x, xb.y, xb.z, xb.w};
        #pragma unroll
        for (int j = 0; j < 8; ++j) {
            #pragma unroll
            for (int o = 0; o < ODIM; ++o)
                acc[o] = fmaf(xs[j], wp[j * ODIM + o], acc[o]);
        }
        xa = na; xb = nb;
    }

    // stage partials: part[wv][o][lane] -> lane-contiguous, conflict-free
    #pragma unroll
    for (int o = 0; o < ODIM; ++o) part[wv][o][lane] = acc[o];
    __syncthreads();

    // cross-wave reduce: thread (wv,lane) handles o = wv + 8c, r = lane.
    // LDS reads lane-contiguous (conflict-free); stores are only 8 KiB/block.
    const float scl = scale_p[0];
    #pragma unroll
    for (int c = 0; c < 4; ++c) {
        int o = wv + NW * c;
        float s = 0.f;
        #pragma unroll
        for (int w2 = 0; w2 < NW; ++w2) s += part[w2][o][lane];
        out[(size_t)row * ODIM + o] = s * scl;
    }
}

// ---------------------------------------------------------------------------
extern "C" void kernel_launch(void* const* d_in, const int* in_sizes, int n_in,
                              void* d_out, int out_size, void* d_ws, size_t ws_size,
                              hipStream_t stream) {
    const float* x = (const float*)d_in[0];
    const float* w = (const float*)d_in[1];
    float* out = (float*)d_out;

    float* wsf     = (float*)d_ws;
    float* partial = wsf;            // 1024 floats
    float* scale   = wsf + 1024;     // 1 float
    float* bwT     = wsf + 2048;     // 8192*32 floats = 1 MiB

    prep_kernel<<<1024, 256, 0, stream>>>(w, bwT, partial);
    scale_kernel<<<1, 256, 0, stream>>>(partial, scale);
    main_kernel<<<BATCH / 64, NW * 64, 0, stream>>>(x, bwT, scale, out);
}

// Round 2
// 197.450 us; speedup vs baseline: 2.9151x; 2.9151x over previous
//
#include <hip/hip_runtime.h>

#define BATCH 16384
#define KDIM  8192
#define ODIM  32
#define SK    4                 // split-K across blocks
#define KSLICE (KDIM / SK)      // 2048 k per block
#define KT    64                // k per LDS tile
#define NTILE (KSLICE / KT)     // 32 tiles
#define RPB   64                // rows per block (= wave size)
#define THREADS 256
#define NWAVE 4
#define KW    (KT / NWAVE)      // 16 k per wave per tile
#define LS    65                // LDS row stride in floats (odd -> conflict-free)

// ---------------------------------------------------------------------------
// Prep 1: bwT[k][o] = sign(w[o][k]) as +-1.0f/0, + per-block partial sum |w|
// ---------------------------------------------------------------------------
__global__ void prep_kernel(const float* __restrict__ w,
                            float* __restrict__ bwT,
                            float* __restrict__ partial) {
    int idx = blockIdx.x * 256 + threadIdx.x;   // coalesced over 32*8192
    int o = idx >> 13;
    int k = idx & (KDIM - 1);
    float v = w[idx];
    float s = (v > 0.f) ? 1.f : ((v < 0.f) ? -1.f : 0.f);
    bwT[(size_t)k * ODIM + o] = s;

    float a = fabsf(v);
    #pragma unroll
    for (int off = 32; off; off >>= 1) a += __shfl_down(a, off, 64);
    __shared__ float red[4];
    int lane = threadIdx.x & 63, wv = threadIdx.x >> 6;
    if (lane == 0) red[wv] = a;
    __syncthreads();
    if (threadIdx.x == 0)
        partial[blockIdx.x] = (red[0] + red[1]) + (red[2] + red[3]);
}

// ---------------------------------------------------------------------------
// Prep 2: deterministic reduce of 1024 partials -> scale = mean(|w|)
// ---------------------------------------------------------------------------
__global__ void scale_kernel(const float* __restrict__ partial,
                             float* __restrict__ scale) {
    int t = threadIdx.x;  // 256 threads
    float a = (partial[t] + partial[t + 256]) + (partial[t + 512] + partial[t + 768]);
    #pragma unroll
    for (int off = 32; off; off >>= 1) a += __shfl_down(a, off, 64);
    __shared__ float red[4];
    if ((t & 63) == 0) red[t >> 6] = a;
    __syncthreads();
    if (t == 0)
        scale[0] = ((red[0] + red[1]) + (red[2] + red[3])) / (float)(ODIM * KDIM);
}

// ---------------------------------------------------------------------------
// Main: coalesced global -> LDS transpose -> lane=row compute with
// wave-uniform (scalar) weights. Split-K partials, no atomics.
// grid = 256 row-groups x SK = 1024 blocks x 256 threads.
// ---------------------------------------------------------------------------
__global__ __launch_bounds__(THREADS, 4)
void main_kernel(const float* __restrict__ x,
                 const float* __restrict__ bwT,
                 float* __restrict__ pout) {
    __shared__ union {
        float buf[2][RPB][LS];        // 2*64*65 = 8320 floats = 33280 B
        float part[NWAVE][ODIM][LS];  // 4*32*65 = 8320 floats (same size)
    } sm;

    const int tid  = threadIdx.x;
    const int rb   = blockIdx.x >> 2;
    const int kb   = blockIdx.x & (SK - 1);
    const size_t rowbase = (size_t)rb * RPB;
    const int kbase = kb * KSLICE;

    const int wv   = __builtin_amdgcn_readfirstlane(tid >> 6);
    const int lane = tid & 63;

    const float* __restrict__ xg = x + rowbase * KDIM + kbase;

    float acc[ODIM];
    #pragma unroll
    for (int o = 0; o < ODIM; ++o) acc[o] = 0.f;

    float4 st[4];

    // prologue: load + write tile 0
    #pragma unroll
    for (int i = 0; i < 4; ++i) {
        int f = tid + THREADS * i, r = f >> 4, k4 = f & 15;
        st[i] = *(const float4*)(xg + (size_t)r * KDIM + k4 * 4);
    }
    #pragma unroll
    for (int i = 0; i < 4; ++i) {
        int f = tid + THREADS * i, r = f >> 4, k4 = f & 15;
        float* d = &sm.buf[0][r][4 * k4];
        d[0] = st[i].x; d[1] = st[i].y; d[2] = st[i].z; d[3] = st[i].w;
    }

    int cur = 0;
    for (int t = 0; t < NTILE; ++t) {
        if (t + 1 < NTILE) {   // issue next tile's global loads (latency hidden by compute)
            #pragma unroll
            for (int i = 0; i < 4; ++i) {
                int f = tid + THREADS * i, r = f >> 4, k4 = f & 15;
                st[i] = *(const float4*)(xg + (size_t)r * KDIM + (t + 1) * KT + k4 * 4);
            }
        }
        __syncthreads();   // buf[cur] fully written

        const float* __restrict__ wk = bwT + (size_t)(kbase + t * KT + wv * KW) * ODIM;
        const float* xr = &sm.buf[cur][lane][wv * KW];
        #pragma unroll
        for (int kk = 0; kk < KW; ++kk) {
            float xv = xr[kk];
            const float* __restrict__ wo = wk + kk * ODIM;   // wave-uniform -> s_load
            #pragma unroll
            for (int o = 0; o < ODIM; ++o)
                acc[o] = fmaf(xv, wo[o], acc[o]);
        }

        if (t + 1 < NTILE) {   // write next tile into the other buffer
            #pragma unroll
            for (int i = 0; i < 4; ++i) {
                int f = tid + THREADS * i, r = f >> 4, k4 = f & 15;
                float* d = &sm.buf[cur ^ 1][r][4 * k4];
                d[0] = st[i].x; d[1] = st[i].y; d[2] = st[i].z; d[3] = st[i].w;
            }
        }
        cur ^= 1;
    }

    // cross-wave reduce via LDS (reuse buffers), then coalesced partial write
    __syncthreads();
    #pragma unroll
    for (int o = 0; o < ODIM; ++o) sm.part[wv][o][lane] = acc[o];
    __syncthreads();

    float* __restrict__ pb = pout + ((size_t)kb * BATCH + rowbase) * ODIM;
    #pragma unroll
    for (int i = 0; i < 8; ++i) {
        int j = tid + THREADS * i;        // j = r*32 + o, fully coalesced
        int r = j >> 5, o = j & 31;
        float s = (sm.part[0][o][r] + sm.part[1][o][r]) +
                  (sm.part[2][o][r] + sm.part[3][o][r]);
        pb[j] = s;
    }
}

// ---------------------------------------------------------------------------
// Final: out = (p0+p1+p2+p3) * scale, float4-vectorized, deterministic
// ---------------------------------------------------------------------------
__global__ void reduce_kernel(const float* __restrict__ pout,
                              const float* __restrict__ scale_p,
                              float* __restrict__ out) {
    const int STRIDE = BATCH * ODIM / 4;          // 131072 float4 per split
    int i = blockIdx.x * 256 + threadIdx.x;       // grid 512 x 256
    const float s = scale_p[0];
    const float4* p = (const float4*)pout;
    float4 a = p[i], b = p[i + STRIDE], c = p[i + 2 * STRIDE], d = p[i + 3 * STRIDE];
    float4 r;
    r.x = ((a.x + b.x) + (c.x + d.x)) * s;
    r.y = ((a.y + b.y) + (c.y + d.y)) * s;
    r.z = ((a.z + b.z) + (c.z + d.z)) * s;
    r.w = ((a.w + b.w) + (c.w + d.w)) * s;
    ((float4*)out)[i] = r;
}

// ---------------------------------------------------------------------------
extern "C" void kernel_launch(void* const* d_in, const int* in_sizes, int n_in,
                              void* d_out, int out_size, void* d_ws, size_t ws_size,
                              hipStream_t stream) {
    const float* x = (const float*)d_in[0];
    const float* w = (const float*)d_in[1];
    float* out = (float*)d_out;

    float* wsf     = (float*)d_ws;
    float* partial = wsf;                    // 1024 floats
    float* scale   = wsf + 1024;             // 1 float
    float* bwT     = wsf + 2048;             // 262144 floats (1 MiB)
    float* pout    = wsf + 2048 + ODIM * KDIM;  // 4 * 524288 floats (8 MiB)

    prep_kernel<<<1024, 256, 0, stream>>>(w, bwT, partial);
    scale_kernel<<<1, 256, 0, stream>>>(partial, scale);
    main_kernel<<<(BATCH / RPB) * SK, THREADS, 0, stream>>>(x, bwT, pout);
    reduce_kernel<<<BATCH * ODIM / 4 / 256, 256, 0, stream>>>(pout, scale, out);
}